// Round 1
// 81.447 us; speedup vs baseline: 1.0620x; 1.0620x over previous
//
#include <hip/hip_runtime.h>
#include <math.h>
#include <float.h>

#define N_RINGS  10
#define N_ANGLES 36
#define NP       (N_RINGS * N_ANGLES)   // 360 points per batch
#define PI_APPROX 3.1415926f

#define BLOCK  256        // 4 waves
#define WPB    4          // waves per block
#define CHUNK  1024       // targets staged per block
#define NPAIR  (CHUNK / 2)
#define PPT    6          // point-slots per lane: 6*64 = 384 >= 360

typedef float f2 __attribute__((ext_vector_type(2)));

// ---------------- kernel A: per-(batch, target-chunk) block --------------
// Each lane owns 6 point slots (l, l+64, ..., l+320). Waves split the staged
// CHUNK of targets in PAIRS; targets staged SoA-paired so each wave-uniform
// ds_read_b128 delivers two aligned f32 register pairs that feed
// v_pk_fma_f32 (2 targets / instruction). Cross-chunk combination via global
// atomicMin on uint bits (d2 >= 0 after clamp, so uint order == float order).
// minbuf pre-set to 0xFFFFFFFF (UINT_MAX) by hipMemsetAsync before launch.
__global__ __launch_bounds__(BLOCK) void chamfer_minbuf(
    const float* __restrict__ pred,    // B x N_RINGS
    const float* __restrict__ target,  // B x N x 3
    unsigned int* __restrict__ minbuf, // B x NP (min d2, uint bits)
    int N, int chunks)
{
    __shared__ float4 txy[NPAIR];         // {x0, x1, y0, y1}
    __shared__ float4 tzw[NPAIR];         // {z0, z1, w0, w1},  w = |t|^2
    __shared__ float  pm[WPB * NP];       // per-wave clamped partial mins
    __shared__ float  cs_c[N_ANGLES], cs_s[N_ANGLES];

    const int b   = blockIdx.x / chunks;
    const int cg  = blockIdx.x % chunks;
    const int n0  = cg * CHUNK;
    const int tid = threadIdx.x;
    const int cnt = min(CHUNK, N - n0);
    const int npairs = (cnt + 1) >> 1;

    if (tid < N_ANGLES) {
        float angf = (float)(10 * tid) * (2.0f * PI_APPROX / 360.0f);
        double ang = (double)angf;
        cs_c[tid] = (float)cos(ang);
        cs_s[tid] = (float)sin(ang);
    }
    // stage target pairs: {x0,x1,y0,y1} and {z0,z1,w0,w1}
    for (int p = tid; p < npairs; p += BLOCK) {
        const int i0 = 2 * p;
        const int i1 = min(2 * p + 1, cnt - 1);   // dup last target if cnt odd
        const float* t0 = target + ((size_t)b * N + (size_t)(n0 + i0)) * 3;
        const float* t1 = target + ((size_t)b * N + (size_t)(n0 + i1)) * 3;
        float x0 = t0[0], y0 = t0[1], z0 = t0[2];
        float x1 = t1[0], y1 = t1[1], z1 = t1[2];
        float w0 = x0 * x0 + y0 * y0 + z0 * z0;
        float w1 = x1 * x1 + y1 * y1 + z1 * z1;
        txy[p] = make_float4(x0, x1, y0, y1);
        tzw[p] = make_float4(z0, z1, w0, w1);
    }
    __syncthreads();

    const int lane = tid & 63;
    const int w    = tid >> 6;

    // q = -2*p so inner pair = pk_fma(qz,Z, pk_fma(qy,Y, pk_fma(qx,X, W)))
    f2 qx2[PPT], qy2[PPT], qz2[PPT], m2[PPT];
    float pp2[PPT];
    #pragma unroll
    for (int k = 0; k < PPT; ++k) {
        int s = lane + 64 * k;
        int j = s / N_ANGLES;
        int a = s - j * N_ANGLES;
        int jc = (j < N_RINGS) ? j : (N_RINGS - 1);   // clamp dummy slots
        float r  = pred[b * N_RINGS + jc];
        float px = -r * cs_c[a] + 0.04f;
        float py = 0.15f * (float)jc - 0.7f;
        float pz = r * cs_s[a];
        pp2[k] = px * px + py * py + pz * pz;
        float qxv = -2.0f * px, qyv = -2.0f * py, qzv = -2.0f * pz;
        qx2[k] = (f2){qxv, qxv};
        qy2[k] = (f2){qyv, qyv};
        qz2[k] = (f2){qzv, qzv};
        m2[k]  = (f2){FLT_MAX, FLT_MAX};
    }

    // waves split the pair list; txy/tzw[k] are wave-uniform -> broadcast
    #pragma unroll 4
    for (int k = w; k < npairs; k += WPB) {
        float4 A  = txy[k];
        float4 Bz = tzw[k];
        f2 X  = {A.x,  A.y };
        f2 Y  = {A.z,  A.w };
        f2 Z  = {Bz.x, Bz.y};
        f2 W2 = {Bz.z, Bz.w};
        #pragma unroll
        for (int i = 0; i < PPT; ++i) {
            f2 h = __builtin_elementwise_fma(qz2[i], Z, W2);
            h = __builtin_elementwise_fma(qy2[i], Y, h);
            h = __builtin_elementwise_fma(qx2[i], X, h);
            m2[i] = __builtin_elementwise_min(m2[i], h);
        }
    }

    // finalize (combine pair halves, add pp2, clamp), publish per-wave partials
    #pragma unroll
    for (int k = 0; k < PPT; ++k) {
        int s = lane + 64 * k;
        if (s < NP) {
            float mv = fminf(m2[k].x, m2[k].y);
            pm[w * NP + s] = fmaxf(pp2[k] + mv, 0.0f);
        }
    }
    __syncthreads();

    // cross-wave min, then one global atomicMin per point
    for (int p = tid; p < NP; p += BLOCK) {
        float v = fminf(fminf(pm[p], pm[NP + p]),
                        fminf(pm[2 * NP + p], pm[3 * NP + p]));
        atomicMin(&minbuf[b * NP + p], __float_as_uint(v));
    }
}

// ---------------- kernel B: mean over B*NP mins (L2-warm, 46 KB) ---------
__global__ __launch_bounds__(1024) void reduce_mean(
    const unsigned int* __restrict__ minbuf, float* __restrict__ out,
    int count)
{
    __shared__ double sm[16];
    const int tid = threadIdx.x;
    double s = 0.0;
    const int n4 = count >> 2;
    const uint4* v4 = (const uint4*)minbuf;
    for (int i = tid; i < n4; i += 1024) {
        uint4 u = v4[i];
        s += (double)__uint_as_float(u.x) + (double)__uint_as_float(u.y)
           + (double)__uint_as_float(u.z) + (double)__uint_as_float(u.w);
    }
    for (int i = 4 * n4 + tid; i < count; i += 1024)
        s += (double)__uint_as_float(minbuf[i]);
    #pragma unroll
    for (int off = 32; off > 0; off >>= 1)
        s += __shfl_down(s, off, 64);
    if ((tid & 63) == 0) sm[tid >> 6] = s;
    __syncthreads();
    if (tid == 0) {
        double tot = 0.0;
        for (int wv = 0; wv < 16; ++wv) tot += sm[wv];
        out[0] = (float)(tot / (double)count);
    }
}

extern "C" void kernel_launch(void* const* d_in, const int* in_sizes, int n_in,
                              void* d_out, int out_size, void* d_ws, size_t ws_size,
                              hipStream_t stream) {
    const float* pred   = (const float*)d_in[0];
    const float* target = (const float*)d_in[1];
    // d_in[2] (trans_feat) unused by the reference.

    const int B = in_sizes[0] / N_RINGS;
    const int N = in_sizes[1] / (3 * B);
    const int chunks = (N + CHUNK - 1) / CHUNK;   // 16 for N=16384
    const int count  = B * NP;                    // 11520

    unsigned int* minbuf = (unsigned int*)d_ws;
    float* out = (float*)d_out;

    // init minbuf to UINT_MAX (graph-capture-safe async memset)
    hipMemsetAsync(minbuf, 0xFF, (size_t)count * sizeof(unsigned int), stream);

    hipLaunchKernelGGL(chamfer_minbuf, dim3(B * chunks), dim3(BLOCK), 0, stream,
                       pred, target, minbuf, N, chunks);
    hipLaunchKernelGGL(reduce_mean, dim3(1), dim3(1024), 0, stream,
                       minbuf, out, count);
}